// Round 10
// baseline (500.775 us; speedup 1.0000x reference)
//
#include <hip/hip_runtime.h>
#include <math.h>

#define NB 8
#define NN 2048
// log2-domain: out = 2^(A*SCALE2 - u2 - v2) == e^(A*20 - u - v).  SCALE2 = 20*log2(e).
#define SCALE2 28.853900817779268f

// ---- X-cached path geometry ----
#define RPWX 4               // rows per wave
#define BROWSX 16            // rows per block (4 waves * RPWX)
#define CHBX (NN / BROWSX)   // 128 partial chunks per matrix

// ---- round-3 fused path geometry (fallback tier 2) ----
#define RPW 8
#define BROWS 32
#define CHB (NN / BROWS)     // 64

// raw-instruction transcendentals: v_exp_f32 is 2^x, v_log_f32 is log2(x).
#if __has_builtin(__builtin_amdgcn_exp2f)
__device__ __forceinline__ float fexp2(float x) { return __builtin_amdgcn_exp2f(x); }
#else
__device__ __forceinline__ float fexp2(float x) { return exp2f(x); }
#endif
#if __has_builtin(__builtin_amdgcn_logf)
__device__ __forceinline__ float flog2(float x) { return __builtin_amdgcn_logf(x); }
#else
__device__ __forceinline__ float flog2(float x) { return log2f(x); }
#endif

__device__ __forceinline__ float wave_max(float x) {
#pragma unroll
    for (int off = 32; off >= 1; off >>= 1)
        x = fmaxf(x, __shfl_xor(x, off, 64));
    return x;
}
__device__ __forceinline__ float wave_sum(float x) {
#pragma unroll
    for (int off = 32; off >= 1; off >>= 1)
        x += __shfl_xor(x, off, 64);
    return x;
}

// =======================================================================
// X-cached path.  X = 2^(A*SCALE2 - m_row), cached in workspace (134 MB).
// Iterations become transcendental-free matvecs:
//   row:  S_i = sum_c X*w_c ;  rS_i = 1/S_i  (= 2^(m_i - u_i))
//   col:  s'_c = sum_i (X*w_c)*rS_i ;  w_new_c = w_old_c * rcp(sum s')
// final: out = X * rS_i * w_c
// =======================================================================

// First pass: compute m, X, rS(iter1, w==1), col partials.
__global__ __launch_bounds__(256, 3) void k0_exp(const float* __restrict__ A,
                                                 float* __restrict__ X,
                                                 float* __restrict__ ru,
                                                 float* __restrict__ ps) {
    const int wid  = threadIdx.x >> 6;
    const int lane = threadIdx.x & 63;
    const int b    = blockIdx.x >> 7;          // 128 blocks per matrix
    const int blk  = blockIdx.x & 127;
    const int row0 = blk * BROWSX + wid * RPWX;

    float s[32];
#pragma unroll
    for (int i = 0; i < 32; ++i) s[i] = 0.f;

    float nxt[32];
    {
        const float4* a4 = (const float4*)(A + ((size_t)b * NN + row0) * NN);
#pragma unroll
        for (int k = 0; k < 8; ++k) {
            float4 a = a4[lane + (k << 6)];
            nxt[4 * k + 0] = a.x; nxt[4 * k + 1] = a.y;
            nxt[4 * k + 2] = a.z; nxt[4 * k + 3] = a.w;
        }
    }

#pragma unroll 1
    for (int r = 0; r < RPWX; ++r) {
        float e[32];
#pragma unroll
        for (int i = 0; i < 32; ++i) e[i] = nxt[i] * SCALE2;

        if (r + 1 < RPWX) {
            const float4* a4 =
                (const float4*)(A + ((size_t)b * NN + row0 + r + 1) * NN);
#pragma unroll
            for (int k = 0; k < 8; ++k) {
                float4 a = a4[lane + (k << 6)];
                nxt[4 * k + 0] = a.x; nxt[4 * k + 1] = a.y;
                nxt[4 * k + 2] = a.z; nxt[4 * k + 3] = a.w;
            }
        }

        float t[16];
#pragma unroll
        for (int i = 0; i < 16; ++i) t[i] = fmaxf(e[i], e[i + 16]);
#pragma unroll
        for (int off = 8; off >= 1; off >>= 1)
#pragma unroll
            for (int i = 0; i < off; ++i) t[i] = fmaxf(t[i], t[i + off]);
        float m = wave_max(t[0]);

#pragma unroll
        for (int i = 0; i < 32; ++i) e[i] = fexp2(e[i] - m);

        // store X row (fire-and-forget)
        float4* xo = (float4*)(X + ((size_t)b * NN + row0 + r) * NN);
#pragma unroll
        for (int k = 0; k < 8; ++k)
            xo[lane + (k << 6)] =
                make_float4(e[4 * k], e[4 * k + 1], e[4 * k + 2], e[4 * k + 3]);

#pragma unroll
        for (int i = 0; i < 16; ++i) t[i] = e[i] + e[i + 16];
#pragma unroll
        for (int off = 8; off >= 1; off >>= 1)
#pragma unroll
            for (int i = 0; i < off; ++i) t[i] += t[i + off];
        float S = wave_sum(t[0]);
        float rS = __builtin_amdgcn_rcpf(S);
        if (lane == 0) ru[b * NN + row0 + r] = rS;
#pragma unroll
        for (int i = 0; i < 32; ++i) s[i] = fmaf(e[i], rS, s[i]);
    }

    __shared__ float4 sm4[4][512];
#pragma unroll
    for (int k = 0; k < 8; ++k)
        sm4[wid][lane + (k << 6)] =
            make_float4(s[4 * k], s[4 * k + 1], s[4 * k + 2], s[4 * k + 3]);
    __syncthreads();

    float4* pbase = (float4*)(ps + ((size_t)b * CHBX + blk) * NN);
#pragma unroll
    for (int gg = 0; gg < 2; ++gg) {
        int g = threadIdx.x + (gg << 8);
        float4 x0 = sm4[0][g], x1 = sm4[1][g], x2 = sm4[2][g], x3 = sm4[3][g];
        float4 o;
        o.x = (x0.x + x1.x) + (x2.x + x3.x);
        o.y = (x0.y + x1.y) + (x2.y + x3.y);
        o.z = (x0.z + x1.z) + (x2.z + x3.z);
        o.w = (x0.w + x1.w) + (x2.w + x3.w);
        pbase[g] = o;
    }
}

// Iterations 2..10: transcendental-free matvec + col partials.
__global__ __launch_bounds__(256, 3) void kI_iter(const float* __restrict__ X,
                                                  const float* __restrict__ w,
                                                  float* __restrict__ ru,
                                                  float* __restrict__ ps) {
    const int wid  = threadIdx.x >> 6;
    const int lane = threadIdx.x & 63;
    const int b    = blockIdx.x >> 7;
    const int blk  = blockIdx.x & 127;
    const int row0 = blk * BROWSX + wid * RPWX;

    float wv[32];
    {
        const float4* w4 = (const float4*)(w + (size_t)b * NN);
#pragma unroll
        for (int k = 0; k < 8; ++k) {
            float4 t = w4[lane + (k << 6)];
            wv[4 * k + 0] = t.x; wv[4 * k + 1] = t.y;
            wv[4 * k + 2] = t.z; wv[4 * k + 3] = t.w;
        }
    }

    float s[32];
#pragma unroll
    for (int i = 0; i < 32; ++i) s[i] = 0.f;

    float nxt[32];
    {
        const float4* x4 = (const float4*)(X + ((size_t)b * NN + row0) * NN);
#pragma unroll
        for (int k = 0; k < 8; ++k) {
            float4 a = x4[lane + (k << 6)];
            nxt[4 * k + 0] = a.x; nxt[4 * k + 1] = a.y;
            nxt[4 * k + 2] = a.z; nxt[4 * k + 3] = a.w;
        }
    }

#pragma unroll 1
    for (int r = 0; r < RPWX; ++r) {
        float p[32];
#pragma unroll
        for (int i = 0; i < 32; ++i) p[i] = nxt[i] * wv[i];

        if (r + 1 < RPWX) {
            const float4* x4 =
                (const float4*)(X + ((size_t)b * NN + row0 + r + 1) * NN);
#pragma unroll
            for (int k = 0; k < 8; ++k) {
                float4 a = x4[lane + (k << 6)];
                nxt[4 * k + 0] = a.x; nxt[4 * k + 1] = a.y;
                nxt[4 * k + 2] = a.z; nxt[4 * k + 3] = a.w;
            }
        }

        float t[16];
#pragma unroll
        for (int i = 0; i < 16; ++i) t[i] = p[i] + p[i + 16];
#pragma unroll
        for (int off = 8; off >= 1; off >>= 1)
#pragma unroll
            for (int i = 0; i < off; ++i) t[i] += t[i + off];
        float S = wave_sum(t[0]);
        float rS = __builtin_amdgcn_rcpf(S);
        if (lane == 0) ru[b * NN + row0 + r] = rS;
#pragma unroll
        for (int i = 0; i < 32; ++i) s[i] = fmaf(p[i], rS, s[i]);
    }

    __shared__ float4 sm4[4][512];
#pragma unroll
    for (int k = 0; k < 8; ++k)
        sm4[wid][lane + (k << 6)] =
            make_float4(s[4 * k], s[4 * k + 1], s[4 * k + 2], s[4 * k + 3]);
    __syncthreads();

    float4* pbase = (float4*)(ps + ((size_t)b * CHBX + blk) * NN);
#pragma unroll
    for (int gg = 0; gg < 2; ++gg) {
        int g = threadIdx.x + (gg << 8);
        float4 x0 = sm4[0][g], x1 = sm4[1][g], x2 = sm4[2][g], x3 = sm4[3][g];
        float4 o;
        o.x = (x0.x + x1.x) + (x2.x + x3.x);
        o.y = (x0.y + x1.y) + (x2.y + x3.y);
        o.z = (x0.z + x1.z) + (x2.z + x3.z);
        o.w = (x0.w + x1.w) + (x2.w + x3.w);
        pbase[g] = o;
    }
}

// w_new_c = (first ? 1 : w_old_c) * rcp( sum over CHBX chunks of ps[b][ch][c] )
__global__ __launch_bounds__(256) void combineX(const float* __restrict__ ps,
                                                float* __restrict__ w, int first) {
    const int l  = threadIdx.x & 31;
    const int g  = threadIdx.x >> 5;           // 0..7
    const int b  = blockIdx.x >> 4;
    const int cb = blockIdx.x & 15;            // 128-col tile
    const float4* pb = (const float4*)(ps + (size_t)b * CHBX * NN)
                     + (size_t)(g * 16) * (NN / 4) + (cb << 5) + l;
    float4 a0 = make_float4(0.f, 0.f, 0.f, 0.f);
    float4 a1 = make_float4(0.f, 0.f, 0.f, 0.f);
#pragma unroll
    for (int i = 0; i < 16; i += 2) {
        float4 x = pb[(size_t)i * (NN / 4)];
        float4 y = pb[(size_t)(i + 1) * (NN / 4)];
        a0.x += x.x; a0.y += x.y; a0.z += x.z; a0.w += x.w;
        a1.x += y.x; a1.y += y.y; a1.z += y.z; a1.w += y.w;
    }
    __shared__ float4 red[8][32];
    float4 c;
    c.x = a0.x + a1.x; c.y = a0.y + a1.y;
    c.z = a0.z + a1.z; c.w = a0.w + a1.w;
    red[g][l] = c;
    __syncthreads();
    if (threadIdx.x < 32) {
        float4 t = red[0][l];
#pragma unroll
        for (int gg = 1; gg < 8; ++gg) {
            float4 rr = red[gg][l];
            t.x += rr.x; t.y += rr.y; t.z += rr.z; t.w += rr.w;
        }
        float4* wp = (float4*)(w + (size_t)b * NN) + (cb << 5) + l;
        float4 wo = first ? make_float4(1.f, 1.f, 1.f, 1.f) : *wp;
        float4 o;
        o.x = wo.x * __builtin_amdgcn_rcpf(t.x);
        o.y = wo.y * __builtin_amdgcn_rcpf(t.y);
        o.z = wo.z * __builtin_amdgcn_rcpf(t.z);
        o.w = wo.w * __builtin_amdgcn_rcpf(t.w);
        *wp = o;
    }
}

// out = X * rS_row * w_col  (no transcendentals)
__global__ __launch_bounds__(256) void finalX(const float* __restrict__ X,
                                              const float* __restrict__ ru,
                                              const float* __restrict__ w,
                                              float* __restrict__ out) {
    const int i4 = blockIdx.x * 256 + threadIdx.x;
    const int r  = i4 >> 9;
    const int c4 = i4 & 511;
    const int b  = r >> 11;
    const float rr = ru[r];
    float4 x  = ((const float4*)X)[i4];
    float4 ww = ((const float4*)(w + (size_t)b * NN))[c4];
    float4 o;
    o.x = x.x * rr * ww.x;
    o.y = x.y * rr * ww.y;
    o.z = x.z * rr * ww.z;
    o.w = x.w * rr * ww.w;
    ((float4*)out)[i4] = o;
}

// =======================================================================
// Round-3 log-domain fused path (fallback tier 2) — unchanged, proven.
// =======================================================================
__global__ __launch_bounds__(256, 2) void fused_iter(const float* __restrict__ A,
                                                     const float* __restrict__ v,
                                                     float* __restrict__ u,
                                                     float* __restrict__ ps) {
    const int wid  = threadIdx.x >> 6;
    const int lane = threadIdx.x & 63;
    const int b    = blockIdx.x >> 6;
    const int blk  = blockIdx.x & 63;
    const int row0 = blk * BROWS + wid * RPW;

    float vv[32];
    {
        const float4* v4 = (const float4*)(v + (size_t)b * NN);
#pragma unroll
        for (int k = 0; k < 8; ++k) {
            float4 t = v4[lane + (k << 6)];
            vv[4 * k + 0] = t.x; vv[4 * k + 1] = t.y;
            vv[4 * k + 2] = t.z; vv[4 * k + 3] = t.w;
        }
    }
    float s[32];
#pragma unroll
    for (int i = 0; i < 32; ++i) s[i] = 0.f;
    float nxt[32];
    {
        const float4* a4 = (const float4*)(A + ((size_t)b * NN + row0) * NN);
#pragma unroll
        for (int k = 0; k < 8; ++k) {
            float4 a = a4[lane + (k << 6)];
            nxt[4 * k + 0] = a.x; nxt[4 * k + 1] = a.y;
            nxt[4 * k + 2] = a.z; nxt[4 * k + 3] = a.w;
        }
    }
#pragma unroll 1
    for (int r = 0; r < RPW; ++r) {
        float e[32];
#pragma unroll
        for (int i = 0; i < 32; ++i) e[i] = fmaf(nxt[i], SCALE2, -vv[i]);
        if (r + 1 < RPW) {
            const float4* a4 =
                (const float4*)(A + ((size_t)b * NN + row0 + r + 1) * NN);
#pragma unroll
            for (int k = 0; k < 8; ++k) {
                float4 a = a4[lane + (k << 6)];
                nxt[4 * k + 0] = a.x; nxt[4 * k + 1] = a.y;
                nxt[4 * k + 2] = a.z; nxt[4 * k + 3] = a.w;
            }
        }
        float t[16];
#pragma unroll
        for (int i = 0; i < 16; ++i) t[i] = fmaxf(e[i], e[i + 16]);
#pragma unroll
        for (int off = 8; off >= 1; off >>= 1)
#pragma unroll
            for (int i = 0; i < off; ++i) t[i] = fmaxf(t[i], t[i + off]);
        float m = wave_max(t[0]);
#pragma unroll
        for (int i = 0; i < 32; ++i) e[i] = fexp2(e[i] - m);
#pragma unroll
        for (int i = 0; i < 16; ++i) t[i] = e[i] + e[i + 16];
#pragma unroll
        for (int off = 8; off >= 1; off >>= 1)
#pragma unroll
            for (int i = 0; i < off; ++i) t[i] += t[i + off];
        float S = wave_sum(t[0]);
        if (lane == 0) u[b * NN + row0 + r] = m + flog2(S);
        float rS = __builtin_amdgcn_rcpf(S);
#pragma unroll
        for (int i = 0; i < 32; ++i) s[i] = fmaf(e[i], rS, s[i]);
    }
    __shared__ float4 sm4[4][512];
#pragma unroll
    for (int k = 0; k < 8; ++k)
        sm4[wid][lane + (k << 6)] =
            make_float4(s[4 * k], s[4 * k + 1], s[4 * k + 2], s[4 * k + 3]);
    __syncthreads();
    float4* pbase = (float4*)(ps + ((size_t)b * CHB + blk) * NN);
#pragma unroll
    for (int gg = 0; gg < 2; ++gg) {
        int g = threadIdx.x + (gg << 8);
        float4 x0 = sm4[0][g], x1 = sm4[1][g], x2 = sm4[2][g], x3 = sm4[3][g];
        float4 o;
        o.x = (x0.x + x1.x) + (x2.x + x3.x);
        o.y = (x0.y + x1.y) + (x2.y + x3.y);
        o.z = (x0.z + x1.z) + (x2.z + x3.z);
        o.w = (x0.w + x1.w) + (x2.w + x3.w);
        pbase[g] = o;
    }
}

__global__ __launch_bounds__(256) void combine(const float* __restrict__ ps,
                                               float* __restrict__ v) {
    const int l  = threadIdx.x & 63;
    const int g  = threadIdx.x >> 6;
    const int b  = blockIdx.x >> 3;
    const int cb = blockIdx.x & 7;
    const float4* pb = (const float4*)(ps + (size_t)b * CHB * NN)
                     + (size_t)(g * 16) * (NN / 4) + (cb << 6) + l;
    float4 a0 = make_float4(0.f, 0.f, 0.f, 0.f);
    float4 a1 = make_float4(0.f, 0.f, 0.f, 0.f);
#pragma unroll
    for (int i = 0; i < 16; i += 2) {
        float4 x = pb[(size_t)i * (NN / 4)];
        float4 y = pb[(size_t)(i + 1) * (NN / 4)];
        a0.x += x.x; a0.y += x.y; a0.z += x.z; a0.w += x.w;
        a1.x += y.x; a1.y += y.y; a1.z += y.z; a1.w += y.w;
    }
    __shared__ float4 red[4][64];
    float4 c;
    c.x = a0.x + a1.x; c.y = a0.y + a1.y;
    c.z = a0.z + a1.z; c.w = a0.w + a1.w;
    red[g][l] = c;
    __syncthreads();
    if (threadIdx.x < 64) {
        float4 r0 = red[0][l], r1 = red[1][l], r2 = red[2][l], r3 = red[3][l];
        float4 t;
        t.x = (r0.x + r1.x) + (r2.x + r3.x);
        t.y = (r0.y + r1.y) + (r2.y + r3.y);
        t.z = (r0.z + r1.z) + (r2.z + r3.z);
        t.w = (r0.w + r1.w) + (r2.w + r3.w);
        float4* vp = (float4*)(v + (size_t)b * NN) + (cb << 6) + l;
        float4 cur = *vp;
        cur.x += flog2(t.x);
        cur.y += flog2(t.y);
        cur.z += flog2(t.z);
        cur.w += flog2(t.w);
        *vp = cur;
    }
}

__global__ __launch_bounds__(256) void row_lse(const float* __restrict__ A,
                                               const float* __restrict__ v,
                                               float* __restrict__ u) {
    const int wid  = threadIdx.x >> 6;
    const int lane = threadIdx.x & 63;
    const int row  = blockIdx.x * 4 + wid;
    const int b    = row >> 11;
    const float4* a4 = (const float4*)(A + (size_t)row * NN);
    const float4* v4 = (const float4*)(v + (size_t)b * NN);
    float x[32];
#pragma unroll
    for (int k = 0; k < 8; ++k) {
        float4 a  = a4[lane + (k << 6)];
        float4 vv = v4[lane + (k << 6)];
        x[4 * k + 0] = fmaf(a.x, SCALE2, -vv.x);
        x[4 * k + 1] = fmaf(a.y, SCALE2, -vv.y);
        x[4 * k + 2] = fmaf(a.z, SCALE2, -vv.z);
        x[4 * k + 3] = fmaf(a.w, SCALE2, -vv.w);
    }
    float m = -INFINITY;
#pragma unroll
    for (int i = 0; i < 32; ++i) m = fmaxf(m, x[i]);
    m = wave_max(m);
    float s = 0.f;
#pragma unroll
    for (int i = 0; i < 32; ++i) s += fexp2(x[i] - m);
    s = wave_sum(s);
    if (lane == 0) u[row] = m + flog2(s);
}

__global__ __launch_bounds__(256) void col_lse(const float* __restrict__ A,
                                               const float* __restrict__ u,
                                               float* __restrict__ v) {
    const int b    = blockIdx.x >> 6;
    const int tile = blockIdx.x & 63;
    const int ci   = threadIdx.x & 31;
    const int rg   = threadIdx.x >> 5;
    const int col  = (tile << 5) + ci;
    const float* Ab = A + (size_t)b * NN * NN;
    const float* ub = u + b * NN;
    float m0 = -INFINITY, s0 = 0.f, m1 = -INFINITY, s1 = 0.f;
    for (int r = rg; r < NN; r += 16) {
        float x0 = fmaf(Ab[(size_t)r * NN + col], SCALE2, -ub[r]);
        float x1 = fmaf(Ab[(size_t)(r + 8) * NN + col], SCALE2, -ub[r + 8]);
        float nm0 = fmaxf(m0, x0);
        s0 = s0 * fexp2(m0 - nm0) + fexp2(x0 - nm0); m0 = nm0;
        float nm1 = fmaxf(m1, x1);
        s1 = s1 * fexp2(m1 - nm1) + fexp2(x1 - nm1); m1 = nm1;
    }
    float m = fmaxf(m0, m1);
    float s = s0 * fexp2(m0 - m) + s1 * fexp2(m1 - m);
    __shared__ float sm[8][33];
    __shared__ float ss[8][33];
    sm[rg][ci] = m; ss[rg][ci] = s;
    __syncthreads();
    if (threadIdx.x < 32) {
        const int c = threadIdx.x;
        float M = sm[0][c], S = ss[0][c];
#pragma unroll
        for (int g = 1; g < 8; ++g) {
            float mg = sm[g][c], sg = ss[g][c];
            float nM = fmaxf(M, mg);
            S = S * fexp2(M - nM) + sg * fexp2(mg - nM);
            M = nM;
        }
        v[b * NN + (tile << 5) + c] = M + flog2(S);
    }
}

__global__ __launch_bounds__(256) void final_exp(const float* __restrict__ A,
                                                 const float* __restrict__ u,
                                                 const float* __restrict__ v,
                                                 float* __restrict__ out) {
    const int i4    = blockIdx.x * 256 + threadIdx.x;
    const int rglob = i4 >> 9;
    const int c4    = i4 & 511;
    const int b     = rglob >> 11;
    const float uu  = u[rglob];
    float4 a  = ((const float4*)A)[i4];
    float4 vv = ((const float4*)(v + (size_t)b * NN))[c4];
    float4 o;
    o.x = fexp2(fmaf(a.x, SCALE2, -uu) - vv.x);
    o.y = fexp2(fmaf(a.y, SCALE2, -uu) - vv.y);
    o.z = fexp2(fmaf(a.z, SCALE2, -uu) - vv.z);
    o.w = fexp2(fmaf(a.w, SCALE2, -uu) - vv.w);
    ((float4*)out)[i4] = o;
}

extern "C" void kernel_launch(void* const* d_in, const int* in_sizes, int n_in,
                              void* d_out, int out_size, void* d_ws, size_t ws_size,
                              hipStream_t stream) {
    const float* A = (const float*)d_in[0];
    float* out = (float*)d_out;

    // X-path layout
    float* ru   = (float*)d_ws;                       // NB*NN
    float* wcol = ru + NB * NN;                       // NB*NN
    float* psX  = wcol + NB * NN;                     // NB*CHBX*NN
    float* X    = psX + (size_t)NB * CHBX * NN;       // NB*NN*NN
    const size_t need_x = ((size_t)2 * NB * NN + (size_t)NB * CHBX * NN +
                           (size_t)NB * NN * NN) * sizeof(float);

    // round-3 layout
    float* u  = (float*)d_ws;
    float* v  = u + NB * NN;
    float* ps = v + NB * NN;
    const size_t need_f =
        ((size_t)2 * NB * NN + (size_t)NB * CHB * NN) * sizeof(float);

    if (ws_size >= need_x) {
        k0_exp<<<NB * 128, 256, 0, stream>>>(A, X, ru, psX);
        combineX<<<NB * 16, 256, 0, stream>>>(psX, wcol, 1);
        for (int it = 1; it < 10; ++it) {
            kI_iter<<<NB * 128, 256, 0, stream>>>(X, wcol, ru, psX);
            combineX<<<NB * 16, 256, 0, stream>>>(psX, wcol, 0);
        }
        finalX<<<NB * NN * NN / 1024, 256, 0, stream>>>(X, ru, wcol, out);
    } else if (ws_size >= need_f) {
        hipMemsetAsync(v, 0, NB * NN * sizeof(float), stream);
        for (int it = 0; it < 10; ++it) {
            fused_iter<<<NB * CHB, 256, 0, stream>>>(A, v, u, ps);
            combine<<<NB * 8, 256, 0, stream>>>(ps, v);
        }
        final_exp<<<NB * NN * NN / 1024, 256, 0, stream>>>(A, u, v, out);
    } else {
        hipMemsetAsync(v, 0, NB * NN * sizeof(float), stream);
        for (int it = 0; it < 10; ++it) {
            row_lse<<<NB * NN / 4, 256, 0, stream>>>(A, v, u);
            col_lse<<<NB * (NN / 32), 256, 0, stream>>>(A, u, v);
        }
        final_exp<<<NB * NN * NN / 1024, 256, 0, stream>>>(A, u, v, out);
    }
}